// Round 13
// baseline (191.913 us; speedup 1.0000x reference)
//
#include <hip/hip_runtime.h>
#include <hip/hip_bf16.h>

// Problem constants (fixed by the reference setup)
#define N_ROWS   500000
#define NR1      25        // nr + 1
#define NGROUPS  20000     // N_ROWS / NR1
#define KCTX     20        // K context indices
#define H        128
#define NODES    10000
#define IDX_COLS 23        // 3 + K

#define RPB      256       // rows per k_main block: two 128-row tiles (R10-best)

typedef __attribute__((ext_vector_type(8))) short short8;   // 8 bf16 = 4 VGPRs
typedef __attribute__((ext_vector_type(4))) float f32x4;    // MFMA C/D

// pack two floats -> two bf16 (RNE) as a 32-bit word
__device__ __forceinline__ unsigned pkbf(float lo, float hi) {
  __hip_bfloat162 h = __float22bfloat162_rn(make_float2(lo, hi));
  union { __hip_bfloat162 h; unsigned u; } c; c.h = h;
  return c.u;
}
__device__ __forceinline__ float bf2f(unsigned short u) {
  union { unsigned u; float f; } c; c.u = ((unsigned)u) << 16; return c.f;
}

// ---------------------------------------------------------------------------
// Kernel A (v6): fused precompute + ctx-means + index pack. Grid (313, 4).
//  y=0..2, x<157 : P[m] = x @ W1m.T via bf16 MFMA, P stored bf16
//  y=0..2, x>=157: idx-pack slice (grid-stride over 500K rows, 468 blocks)
//  y=3           : Cg[g] = b1 + W1c @ mean_g  (mean from fp32 x, L2-resident;
//                  INDEPENDENT of P3 -> fully concurrent with P slices).
//                  64 groups/block, same LDS/MFMA pattern; Cg stored bf16.
// This evicts the ctx phase from k_main (R11 post-mortem: that serial
// pre-barrier stage, not gather latency, was the residual stall).
// ---------------------------------------------------------------------------
#define PN 64
#define PRE_BLOCKS  ((NODES + PN - 1) / PN)      // 157
#define GPB 64
#define CTX_BLOCKS  ((NGROUPS + GPB - 1) / GPB)  // 313
#define PACK_BLOCKS (3 * (CTX_BLOCKS - PRE_BLOCKS))  // 468
__global__ __launch_bounds__(256) void k_precompute(
    const float* __restrict__ x, const float* __restrict__ W1,
    const int* __restrict__ indices, const float* __restrict__ b1,
    unsigned short* __restrict__ Pb, unsigned short* __restrict__ Cgb,
    int2* __restrict__ idx2) {
  const int tid = threadIdx.x;
  const int m   = blockIdx.y;          // 0..2 = P slice / 3 = ctx slice

  if (m < 3 && blockIdx.x >= PRE_BLOCKS) {
    // ---- idx-pack slice on otherwise-idle blocks ----
    const int pid = m * (CTX_BLOCKS - PRE_BLOCKS) + (blockIdx.x - PRE_BLOCKS);
    const int stride = PACK_BLOCKS * 256;
    for (int r = pid * 256 + tid; r < N_ROWS; r += stride) {
      idx2[r] = make_int2(indices[(size_t)r * IDX_COLS + 0],
                          indices[(size_t)r * IDX_COLS + 1]);
    }
    return;
  }

  __shared__ short wlds[128][136];   // bf16 W1slice[j][k], padded: 34.8 KB

  // ---- stage W1 slice -> LDS bf16 (m=3 uses the W1c slice, i.e. m==2) ----
  const int ms = (m == 3) ? 2 : m;
#pragma unroll
  for (int it = 0; it < 16; ++it) {
    const int f  = it * 256 + tid;
    const int j  = f >> 5;
    const int q4 = f & 31;
    const float4 v = *(const float4*)(W1 + (size_t)j * (3 * H) + ms * H + q4 * 4);
    *(unsigned*)&wlds[j][q4 * 4]     = pkbf(v.x, v.y);
    *(unsigned*)&wlds[j][q4 * 4 + 2] = pkbf(v.z, v.w);
  }
  __syncthreads();

  const int lane = tid & 63;
  const int wv   = tid >> 6;
  const int col  = lane & 15;
  const int quad = lane >> 4;

  short8 Af[4];
  if (m < 3) {
    // ---- P slice: A-rows = x nodes (bf16-converted on the fly) ----
    int node = blockIdx.x * PN + wv * 16 + col;
    if (node > NODES - 1) node = NODES - 1;
    const float4* __restrict__ xr = (const float4*)(x + (size_t)node * H);
#pragma unroll
    for (int kt = 0; kt < 4; ++kt) {
      const int f4 = kt * 8 + quad * 2;
      const float4 v0 = xr[f4], v1 = xr[f4 + 1];
      union { short8 v; unsigned u[4]; } pk;
      pk.u[0] = pkbf(v0.x, v0.y);
      pk.u[1] = pkbf(v0.z, v0.w);
      pk.u[2] = pkbf(v1.x, v1.y);
      pk.u[3] = pkbf(v1.z, v1.w);
      Af[kt] = pk.v;
    }
  } else {
    // ---- ctx slice: A-rows = group means (x fp32, L2-resident) ----
    int g = blockIdx.x * GPB + wv * 16 + col;
    if (g > NGROUPS - 1) g = NGROUPS - 1;
    const int* __restrict__ rowidx = indices + (size_t)g * NR1 * IDX_COLS + 3;
    int idxs[KCTX];
    int cnt = 0;
#pragma unroll
    for (int c = 0; c < KCTX; ++c) {
      idxs[c] = rowidx[c];
      cnt += (idxs[c] > 0) ? 1 : 0;
    }
    const float rn = 1.f / (float)((cnt > 1) ? cnt : 1);
#pragma unroll
    for (int kt = 0; kt < 4; ++kt) {
      float s[8];
#pragma unroll
      for (int e = 0; e < 8; ++e) s[e] = 0.f;
#pragma unroll
      for (int c = 0; c < KCTX; ++c) {
        const float4* __restrict__ xr =
            (const float4*)(x + (size_t)idxs[c] * H + kt * 32 + quad * 8);
        const float4 v0 = xr[0], v1 = xr[1];
        s[0] += v0.x; s[1] += v0.y; s[2] += v0.z; s[3] += v0.w;
        s[4] += v1.x; s[5] += v1.y; s[6] += v1.z; s[7] += v1.w;
      }
      union { short8 v; unsigned u[4]; } pk;
      pk.u[0] = pkbf(s[0] * rn, s[1] * rn);
      pk.u[1] = pkbf(s[2] * rn, s[3] * rn);
      pk.u[2] = pkbf(s[4] * rn, s[5] * rn);
      pk.u[3] = pkbf(s[6] * rn, s[7] * rn);
      Af[kt] = pk.v;
    }
  }

  f32x4 acc[8];
#pragma unroll
  for (int ct = 0; ct < 8; ++ct) acc[ct] = (f32x4)(0.f);

#pragma unroll
  for (int kt = 0; kt < 4; ++kt) {
#pragma unroll
    for (int ct = 0; ct < 8; ++ct) {
      const short8 Bf = *(const short8*)&wlds[ct * 16 + col][kt * 32 + quad * 8];
      acc[ct] = __builtin_amdgcn_mfma_f32_16x16x32_bf16(Af[kt], Bf, acc[ct], 0, 0, 0);
    }
  }

  if (m < 3) {
    unsigned short* __restrict__ Pm = Pb + (size_t)m * NODES * H;
#pragma unroll
    for (int reg = 0; reg < 4; ++reg) {
      const int n = blockIdx.x * PN + wv * 16 + quad * 4 + reg;
      if (n < NODES) {
#pragma unroll
        for (int ct = 0; ct < 8; ++ct) {
          union { unsigned u; unsigned short s[2]; } c;
          c.u = pkbf(acc[ct][reg], 0.f);
          Pm[(size_t)n * H + ct * 16 + col] = c.s[0];
        }
      }
    }
  } else {
    // Cg = acc + b1, stored bf16 (b1 folded so k_main adds nothing)
    float b1v[8];
#pragma unroll
    for (int ct = 0; ct < 8; ++ct) b1v[ct] = b1[ct * 16 + col];
#pragma unroll
    for (int reg = 0; reg < 4; ++reg) {
      const int g = blockIdx.x * GPB + wv * 16 + quad * 4 + reg;
      if (g < NGROUPS) {
#pragma unroll
        for (int ct = 0; ct < 8; ++ct) {
          union { unsigned u; unsigned short s[2]; } c;
          c.u = pkbf(acc[ct][reg] + b1v[ct], 0.f);
          Cgb[(size_t)g * H + ct * 16 + col] = c.s[0];
        }
      }
    }
  }
}

// ---------------------------------------------------------------------------
// Kernel C (v12): two-tile pipelined main kernel, NO ctx phase.
//  Pre-barrier: W2 -> LDS bf16 only (coalesced, no gather-dependent chain).
//  ONE barrier. Then per tile: gathers (P1,P2,Cg — all bf16 short8) -> A ->
//  issue next tile's gathers -> MFMA + epilogue + store.
//  Cg gathers have 25-row locality -> L1-hot. LDS 17.4 KB -> ~9 blocks/CU.
// Block = 256 threads (4 waves); wave w owns rows [t*128 + w*32, +32).
// ---------------------------------------------------------------------------
__global__ __launch_bounds__(256) void k_main(
    const int2* __restrict__ idx2,
    const unsigned short* __restrict__ P1b, const unsigned short* __restrict__ P2b,
    const unsigned short* __restrict__ Cgb,
    const float* __restrict__ W2, const float* __restrict__ b2,
    const float* __restrict__ W3, const float* __restrict__ b3,
    float* __restrict__ out) {
  __shared__ short w2s[64][136];   // bf16 W2[n][k], padded: 17.4 KB

  const int tid   = threadIdx.x;
  const int rbase = blockIdx.x * RPB;

  // ---- pre-barrier: W2 -> LDS bf16 (coalesced float2 reads) ----
  for (int idx = tid; idx < 64 * 64; idx += 256) {
    const int n  = idx >> 6;
    const int kp = idx & 63;
    const float2 w = *(const float2*)(W2 + (size_t)n * H + kp * 2);
    *(unsigned*)&w2s[n][kp * 2] = pkbf(w.x, w.y);
  }
  __syncthreads();

  const int lane = tid & 63;
  const int wv   = tid >> 6;
  const int col  = lane & 15;
  const int quad = lane >> 4;

  // epilogue constants (L1-hot, load once)
  float b2v[4], w3v[4];
#pragma unroll
  for (int ct = 0; ct < 4; ++ct) {
    b2v[ct] = b2[ct * 16 + col];
    w3v[ct] = W3[ct * 16 + col];
  }
  const float bias3 = b3[0];

  // ping-pong gather buffers (P1, P2, Cg)
  short8 ua[2][2][4], ub[2][2][4], uc[2][2][4];

  // issue tile-0 gathers
  {
    const int R = rbase + wv * 32;
#pragma unroll
    for (int rt = 0; rt < 2; ++rt) {
      const int r  = R + rt * 16 + col;
      const int rc = (r < N_ROWS) ? r : (N_ROWS - 1);
      const int2 ii = idx2[rc];
      const int g   = rc / NR1;
      const short8* __restrict__ pa = (const short8*)(P1b + (size_t)ii.x * H);
      const short8* __restrict__ pb = (const short8*)(P2b + (size_t)ii.y * H);
      const short8* __restrict__ pc = (const short8*)(Cgb + (size_t)g * H);
#pragma unroll
      for (int kt = 0; kt < 4; ++kt) {
        ua[0][rt][kt] = pa[kt * 4 + quad];
        ub[0][rt][kt] = pb[kt * 4 + quad];
        uc[0][rt][kt] = pc[kt * 4 + quad];
      }
    }
  }

#pragma unroll
  for (int t = 0; t < 2; ++t) {
    const int cur = t & 1;
    const int nxt = cur ^ 1;
    const int Rt  = rbase + t * 128 + wv * 32;

    // ---- build A-fragments for tile t (waits on its gathers only) ----
    short8 A[2][4];
#pragma unroll
    for (int rt = 0; rt < 2; ++rt) {
#pragma unroll
      for (int kt = 0; kt < 4; ++kt) {
        union { short8 v; unsigned short s[8]; } va, vb, vc;
        va.v = ua[cur][rt][kt];
        vb.v = ub[cur][rt][kt];
        vc.v = uc[cur][rt][kt];
        union { short8 v; unsigned u[4]; } pk;
#pragma unroll
        for (int e = 0; e < 4; ++e) {
          const float h0 = fmaxf(bf2f(va.s[2 * e])     + bf2f(vb.s[2 * e])
                                 + bf2f(vc.s[2 * e]), 0.f);
          const float h1 = fmaxf(bf2f(va.s[2 * e + 1]) + bf2f(vb.s[2 * e + 1])
                                 + bf2f(vc.s[2 * e + 1]), 0.f);
          pk.u[e] = pkbf(h0, h1);
        }
        A[rt][kt] = pk.v;
      }
    }

    // ---- issue tile t+1 gathers (latency hides behind tile-t MFMA) ----
    if (t + 1 < 2) {
      const int Rn = rbase + (t + 1) * 128 + wv * 32;
#pragma unroll
      for (int rt = 0; rt < 2; ++rt) {
        const int r  = Rn + rt * 16 + col;
        const int rc = (r < N_ROWS) ? r : (N_ROWS - 1);
        const int2 ii = idx2[rc];
        const int g   = rc / NR1;
        const short8* __restrict__ pa = (const short8*)(P1b + (size_t)ii.x * H);
        const short8* __restrict__ pb = (const short8*)(P2b + (size_t)ii.y * H);
        const short8* __restrict__ pc = (const short8*)(Cgb + (size_t)g * H);
#pragma unroll
        for (int kt = 0; kt < 4; ++kt) {
          ua[nxt][rt][kt] = pa[kt * 4 + quad];
          ub[nxt][rt][kt] = pb[kt * 4 + quad];
          uc[nxt][rt][kt] = pc[kt * 4 + quad];
        }
      }
    }

    // ---- MFMA layer 2 + epilogue + store for tile t ----
    f32x4 acc[2][4];
#pragma unroll
    for (int rt = 0; rt < 2; ++rt)
#pragma unroll
      for (int ct = 0; ct < 4; ++ct) acc[rt][ct] = (f32x4)(0.f);
#pragma unroll
    for (int kt = 0; kt < 4; ++kt) {
#pragma unroll
      for (int ct = 0; ct < 4; ++ct) {
        const short8 Bf = *(const short8*)&w2s[ct * 16 + col][kt * 32 + quad * 8];
#pragma unroll
        for (int rt = 0; rt < 2; ++rt)
          acc[rt][ct] = __builtin_amdgcn_mfma_f32_16x16x32_bf16(
              A[rt][kt], Bf, acc[rt][ct], 0, 0, 0);
      }
    }
#pragma unroll
    for (int rt = 0; rt < 2; ++rt) {
#pragma unroll
      for (int reg = 0; reg < 4; ++reg) {
        float s = 0.f;
#pragma unroll
        for (int ct = 0; ct < 4; ++ct)
          s += fmaxf(acc[rt][ct][reg] + b2v[ct], 0.f) * w3v[ct];
        s += __shfl_xor(s, 1);
        s += __shfl_xor(s, 2);
        s += __shfl_xor(s, 4);
        s += __shfl_xor(s, 8);
        if (col == 0) {
          const int row = Rt + rt * 16 + quad * 4 + reg;   // C row = quad*4+reg
          if (row < N_ROWS) out[row] = s + bias3;
        }
      }
    }
  }
}

// ---------------------------------------------------------------------------
extern "C" void kernel_launch(void* const* d_in, const int* in_sizes, int n_in,
                              void* d_out, int out_size, void* d_ws, size_t ws_size,
                              hipStream_t stream) {
  const int*   indices = (const int*)  d_in[0];
  // d_in[1] = nr (scalar, fixed at 24)
  const float* x  = (const float*)d_in[2];
  const float* W1 = (const float*)d_in[3];
  const float* b1 = (const float*)d_in[4];
  const float* W2 = (const float*)d_in[5];
  const float* b2 = (const float*)d_in[6];
  const float* W3 = (const float*)d_in[7];
  const float* b3 = (const float*)d_in[8];
  float* out = (float*)d_out;

  // Workspace: Pb (bf16 7.68 MB) | Cgb (bf16 5.12 MB) | idx2 (4 MB)
  unsigned short* Pb  = (unsigned short*)d_ws;
  unsigned short* P1b = Pb;
  unsigned short* P2b = Pb + (size_t)NODES * H;
  unsigned short* Cgb = Pb + (size_t)3 * NODES * H;
  int2* idx2 = (int2*)(Cgb + (size_t)NGROUPS * H);

  dim3 gpre(CTX_BLOCKS, 4);   // y=0..2: P slices (+idx pack), y=3: Cg slice
  k_precompute<<<gpre, 256, 0, stream>>>(x, W1, indices, b1, Pb, Cgb, idx2);
  k_main<<<(N_ROWS + RPB - 1) / RPB, 256, 0, stream>>>(idx2, P1b, P2b, Cgb,
                                                       W2, b2, W3, b3, out);
}